// Round 16
// baseline (222.397 us; speedup 1.0000x reference)
//
#include <hip/hip_runtime.h>
#include <hip/hip_bf16.h>

#define B_  32
#define N_  577
#define D_  768
#define H_  12
#define HD_ 64
#define M_  (B_ * N_)        // 18464 rows
#define NW_ (3 * D_)         // 2304 fused output cols (q|k|v)
#define VN_ 640              // padded V row stride
#define BPAD_ 640            // bias: padded q-rows AND key-cols
#define SCALE_ 0.18033688f   // 0.125 * log2(e)  (pre-applied to Q)

typedef __bf16 bf16_t;
typedef __bf16 bf16x8 __attribute__((ext_vector_type(8)));
typedef __bf16 bf16x4 __attribute__((ext_vector_type(4)));
typedef float  f32x4  __attribute__((ext_vector_type(4)));

static __device__ __forceinline__ bf16x8 ldg8(const bf16_t* p) {
    return *reinterpret_cast<const bf16x8*>(p);
}

// nontemporal store: outputs bypass/minimize L2 residency so the staged
// read working set (A-panel + W in GEMM; K/V/bias in attn) stays L2-hot.
template <typename T>
static __device__ __forceinline__ void stnt(T* p, T v) {
    __builtin_nontemporal_store(v, p);
}

// within-64 key permutation: LDS K-slot s holds global key g(s) so that the
// swapped-QK output registers are directly the PV A-fragment (natural V order)
#define GPERM(r) (((r) & 32) | (((r) & 8) << 1) | (((r) & 4) << 1) | \
                  (((r) & 16) >> 2) | ((r) & 3))

#define GLOAD_LDS16(g, l)                                                     \
    __builtin_amdgcn_global_load_lds(                                         \
        (const __attribute__((address_space(1))) void*)(g),                   \
        (__attribute__((address_space(3))) void*)(l), 16, 0, 0)

// ---------------------------------------------------------------- fp32->bf16
__global__ void cvt_f32_bf16(const float* __restrict__ src,
                             bf16_t* __restrict__ dst, int n4) {
    int i = blockIdx.x * blockDim.x + threadIdx.x;
    if (i < n4) {
        float4 f = reinterpret_cast<const float4*>(src)[i];
        bf16x4 o;
        o.x = (bf16_t)f.x; o.y = (bf16_t)f.y; o.z = (bf16_t)f.z; o.w = (bf16_t)f.w;
        *reinterpret_cast<bf16x4*>(dst + (size_t)i * 4) = o;
    }
}

__global__ void cvt3_f32_bf16(const float* __restrict__ s0,
                              const float* __restrict__ s1,
                              const float* __restrict__ s2,
                              bf16_t* __restrict__ dst, int n4) {
    int i = blockIdx.x * blockDim.x + threadIdx.x;
    if (i < n4) {
        const float* src = blockIdx.y == 0 ? s0 : (blockIdx.y == 1 ? s1 : s2);
        float4 f = reinterpret_cast<const float4*>(src)[i];
        bf16x4 o;
        o.x = (bf16_t)f.x; o.y = (bf16_t)f.y; o.z = (bf16_t)f.z; o.w = (bf16_t)f.w;
        *reinterpret_cast<bf16x4*>(dst + (size_t)blockIdx.y * n4 * 4 + (size_t)i * 4) = o;
    }
}

// ---------------------------------------------------------------- bias build
// bias2[h][q][kl]: kl is the PERMUTED key slot (gk = (kl&~63)|GPERM(kl&63));
// slots whose global key >= N_ get -1e30 (kills padded keys via MFMA C-init).
__global__ void build_bias2(const float* __restrict__ table,
                            const int* __restrict__ idx,
                            float* __restrict__ bias2) {
    int q = blockIdx.x;                    // 0..639
    int rr = q < N_ ? q : (N_ - 1);
    for (int kl = threadIdx.x; kl < BPAD_; kl += blockDim.x) {
        int s = kl & 63;
        int gk = (kl & ~63) | GPERM(s);
        if (gk < N_) {
            int id = idx[rr * N_ + gk];
            const float* trow = table + (size_t)id * H_;
#pragma unroll
            for (int h = 0; h < H_; ++h)
                bias2[((size_t)h * BPAD_ + q) * BPAD_ + kl] =
                    trow[h] * 1.44269504f;
        } else {
#pragma unroll
            for (int h = 0; h < H_; ++h)
                bias2[((size_t)h * BPAD_ + q) * BPAD_ + kl] = -1e30f;
        }
    }
}

// ---------------------------------------------------------------- QKV GEMM
// (round-13 structure: 128x128 tile, BK=64, dbuf + counted vmcnt(8);
//  epilogue stores are NONTEMPORAL so A-panel/W stay L2-resident)
__global__ __launch_bounds__(256) void qkv_gemm(
    const bf16_t* __restrict__ hb, const bf16_t* __restrict__ W,
    const float* __restrict__ qb, const float* __restrict__ vb,
    bf16_t* __restrict__ Q, bf16_t* __restrict__ K, bf16_t* __restrict__ VT)
{
    __shared__ __align__(16) char lds[65536];  // A:[2][16K] @0, B:[2][16K] @32K

    int tid = threadIdx.x;
    int w  = tid >> 6, l = tid & 63;
    int lr = l & 15, lg = l >> 4;
    int wm = w & 1,  wn = w >> 1;

    int wg = blockIdx.x;
    int xcd = wg & 7, pos = wg >> 3;
    const int Q8 = 2610 / 8, R8 = 2610 % 8;   // 326, 2
    int base = xcd < R8 ? xcd * (Q8 + 1) : R8 * (Q8 + 1) + (xcd - R8) * Q8;
    int wgid = base + pos;
    int bx = wgid / 18, y = wgid - bx * 18;
    int brow = bx * 128;
    int mat = y / 6, ysub = y - mat * 6;
    int cbase = ysub * 128;

    int srow = tid >> 3;
    int sslot = (tid & 7) ^ (srow & 7);
    const bf16_t* pa[4];
    const bf16_t* pb[4];
#pragma unroll
    for (int r = 0; r < 4; ++r) {
        int ra = brow + r * 32 + srow; ra = ra < M_ ? ra : (M_ - 1);
        pa[r] = hb + (size_t)ra * D_ + sslot * 8;
        pb[r] = W + (size_t)(y * 128 + r * 32 + srow) * D_ + sslot * 8;
    }

    auto stage = [&](int buf, int k) {
#pragma unroll
        for (int r = 0; r < 4; ++r) {
            GLOAD_LDS16(pa[r] + k, lds + buf * 16384 + r * 4096 + tid * 16);
            GLOAD_LDS16(pb[r] + k, lds + 32768 + buf * 16384 + r * 4096 + tid * 16);
        }
    };

    f32x4 acc[4][4] = {};
    stage(0, 0);
    int cur = 0;
    for (int t = 0; t < 12; ++t) {
        if (t < 11) {
            stage(cur ^ 1, (t + 1) * 64);
            asm volatile("s_waitcnt vmcnt(8)" ::: "memory");
        } else {
            asm volatile("s_waitcnt vmcnt(0)" ::: "memory");
        }
        __builtin_amdgcn_s_barrier();
        __builtin_amdgcn_sched_barrier(0);

        const char* pA = lds + cur * 16384;
        const char* pB = lds + 32768 + cur * 16384;
#pragma unroll
        for (int kk = 0; kk < 2; ++kk) {
            bf16x8 af[4];
#pragma unroll
            for (int m = 0; m < 4; ++m) {
                int row = wm * 64 + m * 16 + lr;
                af[m] = *reinterpret_cast<const bf16x8*>(
                    pA + row * 128 + (((kk * 4 + lg) ^ (lr & 7)) << 4));
            }
#pragma unroll
            for (int n = 0; n < 4; ++n) {
                int row = wn * 64 + n * 16 + lr;
                bf16x8 bfr = *reinterpret_cast<const bf16x8*>(
                    pB + row * 128 + (((kk * 4 + lg) ^ (lr & 7)) << 4));
#pragma unroll
                for (int m = 0; m < 4; ++m)
                    acc[m][n] = __builtin_amdgcn_mfma_f32_16x16x32_bf16(
                        af[m], bfr, acc[m][n], 0, 0, 0);
            }
        }
        __builtin_amdgcn_sched_barrier(0);
        __builtin_amdgcn_s_barrier();
        cur ^= 1;
    }

    bf16_t* ep = (bf16_t*)lds;
    if (mat < 2) {
#pragma unroll
        for (int m = 0; m < 4; ++m)
#pragma unroll
            for (int n = 0; n < 4; ++n) {
                int col = wn * 64 + n * 16 + lr;
#pragma unroll
                for (int j = 0; j < 4; ++j) {
                    int row = wm * 64 + m * 16 + lg * 4 + j;
                    float v = acc[m][n][j];
                    v = (mat == 0) ? (v + qb[cbase + col]) * SCALE_ : v;
                    ep[row * 132 + col] = (bf16_t)v;
                }
            }
        __syncthreads();
        bf16_t* dst0 = (mat == 0) ? Q : K;
#pragma unroll
        for (int k = 0; k < 8; ++k) {
            int c = k * 256 + tid;
            int row = c >> 4, cc = c & 15;
            int grow = brow + row;
            if (grow < M_) {
                int bb = grow / N_, nn = grow - bb * N_;
                int col0 = cc * 8;
                int hh = ysub * 2 + (col0 >> 6);
                int hd0 = col0 & 63;
                bf16x8 vc = *reinterpret_cast<const bf16x8*>(ep + row * 132 + col0);
                stnt(reinterpret_cast<bf16x8*>(
                    dst0 + ((size_t)(bb * H_ + hh) * N_ + nn) * HD_ + hd0), vc);
            }
        }
    } else {
#pragma unroll
        for (int m = 0; m < 4; ++m)
#pragma unroll
            for (int n = 0; n < 4; ++n) {
                int col = wn * 64 + n * 16 + lr;
                float badd = vb[cbase + col];
#pragma unroll
                for (int j = 0; j < 4; ++j) {
                    int row = wm * 64 + m * 16 + lg * 4 + j;
                    ep[col * 132 + row] = (bf16_t)(acc[m][n][j] + badd);
                }
            }
        __syncthreads();
#pragma unroll
        for (int k = 0; k < 8; ++k) {
            int c = k * 256 + tid;
            int col = c >> 4, rc = c & 15;
            int grow0 = brow + rc * 8;
            int hh = ysub * 2 + (col >> 6), hd = col & 63;
            int bb = grow0 / N_, nn0 = grow0 - bb * N_;
            if (nn0 + 8 <= N_ && grow0 + 8 <= M_) {
                stnt(reinterpret_cast<bf16x8*>(
                         VT + ((size_t)(bb * H_ + hh) * HD_ + hd) * VN_ + nn0),
                     *reinterpret_cast<const bf16x8*>(ep + col * 132 + rc * 8));
            } else {
                for (int jj = 0; jj < 8; ++jj) {
                    int grow = grow0 + jj;
                    if (grow >= M_) break;
                    int b2 = grow / N_, n2 = grow - b2 * N_;
                    stnt(&VT[((size_t)(b2 * H_ + hh) * HD_ + hd) * VN_ + n2],
                         ep[col * 132 + rc * 8 + jj]);
                }
            }
        }
    }
}

// ---------------------------------------------------------------- attention
// Swapped-QK^T with key-permuted K tile (round-15, best): P in registers,
// one-barrier pipeline, K,V dbuf, bias reg-dbuf; out stores NONTEMPORAL.
__global__ __launch_bounds__(256) void attn(
    const bf16_t* __restrict__ Q, const bf16_t* __restrict__ K,
    const bf16_t* __restrict__ VT, const float* __restrict__ bias2,
    float* __restrict__ out)
{
    __shared__ __align__(16) char Kl[2][8192];   // [64 key-slot][64 hd] swz
    __shared__ __align__(16) char Vl[2][8192];   // [64 d][64 key] swz
    // 32768 B -> 5 blocks/CU

    int tid = threadIdx.x;
    int w = tid >> 6, l = tid & 63, lr = l & 15, lg = l >> 4;

    int wg = blockIdx.x;
    int wgid = (wg & 7) * 480 + (wg >> 3);
    int h = wgid / 320;
    int rem = wgid - h * 320;
    int b = rem / 10;
    int qt = rem - b * 10;

    const bf16_t* Qp = Q  + (size_t)(b * H_ + h) * N_ * HD_;
    const bf16_t* Kp = K  + (size_t)(b * H_ + h) * N_ * HD_;
    const bf16_t* Vp = VT + (size_t)(b * H_ + h) * HD_ * VN_;
    const float*  bp = bias2 + (size_t)h * BPAD_ * BPAD_;   // [q][kl]

    int q0 = qt * 64 + w * 16;
    int qrow = q0 + lr;
    int qrow_c = qrow < N_ ? qrow : (N_ - 1);
    bf16x8 aQ0 = ldg8(Qp + (size_t)qrow_c * HD_ + lg * 8);
    bf16x8 aQ1 = ldg8(Qp + (size_t)qrow_c * HD_ + 32 + lg * 8);

    bf16x8 vone;
#pragma unroll
    for (int i = 0; i < 8; ++i) vone[i] = (bf16_t)1.0f;

    int rloc = l >> 3;
    int cswz = (l & 7) ^ rloc;
    const bf16_t* Kst[2];
    const bf16_t* Vst[2];
#pragma unroll
    for (int rnd = 0; rnd < 2; ++rnd) {
        int r = rnd * 32 + w * 8 + rloc;         // LDS key-slot row
        int gk = GPERM(r);                        // global key for this slot
        Kst[rnd] = Kp + (size_t)gk * HD_ + cswz * 8;   // unclamped (padded buf)
        Vst[rnd] = Vp + (size_t)r * VN_ + cswz * 8;    // V natural (rows = d)
    }

    f32x4 o[4] = {};
    f32x4 osum = {};
    const int NT = 10;

    auto stageKV = [&](int buf, int k0) {
#pragma unroll
        for (int rnd = 0; rnd < 2; ++rnd)
            GLOAD_LDS16(Kst[rnd] + (size_t)k0 * HD_,
                        Kl[buf] + rnd * 4096 + w * 1024);
#pragma unroll
        for (int rnd = 0; rnd < 2; ++rnd)
            GLOAD_LDS16(Vst[rnd] + k0, Vl[buf] + rnd * 4096 + w * 1024);
    };
    auto loadBias = [&](int k0, f32x4* bbv) {
        const float* brow = bp + (size_t)(q0 + lr) * BPAD_ + k0;
#pragma unroll
        for (int kt = 0; kt < 4; ++kt)
            bbv[kt] = *reinterpret_cast<const f32x4*>(brow + kt * 16 + lg * 4);
    };

    auto tile = [&](int t, int rbuf, const f32x4* bbcur, f32x4* bbnxt) {
        int k0 = t * 64;
        if (t + 1 < NT) {
            stageKV(rbuf ^ 1, k0 + 64);
            loadBias(k0 + 64, bbnxt);
        }
        __builtin_amdgcn_sched_barrier(0);

        // S^T = K Q^T + bias2 (swapped operands: D col = q, row = key-slot)
        f32x4 s[4];
        __builtin_amdgcn_s_setprio(1);
#pragma unroll
        for (int kt = 0; kt < 4; ++kt) {
            int r = kt * 16 + lr;                // key-slot row in Kl
            bf16x8 kf0 = *reinterpret_cast<const bf16x8*>(
                Kl[rbuf] + r * 128 + ((lg ^ (r & 7)) << 4));
            bf16x8 kf1 = *reinterpret_cast<const bf16x8*>(
                Kl[rbuf] + r * 128 + (((4 + lg) ^ (r & 7)) << 4));
            f32x4 a = __builtin_amdgcn_mfma_f32_16x16x32_bf16(
                kf0, aQ0, bbcur[kt], 0, 0, 0);
            s[kt] = __builtin_amdgcn_mfma_f32_16x16x32_bf16(kf1, aQ1, a, 0, 0, 0);
        }
        __builtin_amdgcn_s_setprio(0);

        // P = exp2(s) stays in registers; lane's s[2kc],[2kc+1] are the PV
        // A-fragment for keys kc*32 + lg*8 + (0..7) in natural V order.
        float p[4][4];
#pragma unroll
        for (int kt = 0; kt < 4; ++kt)
#pragma unroll
            for (int j = 0; j < 4; ++j)
                p[kt][j] = __builtin_amdgcn_exp2f(s[kt][j]);

        // O += P V ; row-sum += P * ones
        __builtin_amdgcn_s_setprio(1);
#pragma unroll
        for (int kc = 0; kc < 2; ++kc) {
            bf16x8 aP;
            aP[0] = (bf16_t)p[2 * kc][0];
            aP[1] = (bf16_t)p[2 * kc][1];
            aP[2] = (bf16_t)p[2 * kc][2];
            aP[3] = (bf16_t)p[2 * kc][3];
            aP[4] = (bf16_t)p[2 * kc + 1][0];
            aP[5] = (bf16_t)p[2 * kc + 1][1];
            aP[6] = (bf16_t)p[2 * kc + 1][2];
            aP[7] = (bf16_t)p[2 * kc + 1][3];
            osum = __builtin_amdgcn_mfma_f32_16x16x32_bf16(aP, vone, osum, 0, 0, 0);
#pragma unroll
            for (int ft = 0; ft < 4; ++ft) {
                int d = ft * 16 + lr;
                bf16x8 bV = *reinterpret_cast<const bf16x8*>(
                    Vl[rbuf] + d * 128 + (((kc * 4 + lg) ^ (d & 7)) << 4));
                o[ft] = __builtin_amdgcn_mfma_f32_16x16x32_bf16(aP, bV, o[ft], 0, 0, 0);
            }
        }
        __builtin_amdgcn_s_setprio(0);
        __builtin_amdgcn_sched_barrier(0);

        if (t + 1 < NT) asm volatile("s_waitcnt vmcnt(4)" ::: "memory");
        else            asm volatile("s_waitcnt vmcnt(0)" ::: "memory");
        __builtin_amdgcn_s_barrier();
        __builtin_amdgcn_sched_barrier(0);
    };

    f32x4 bbA[4], bbB[4];
    stageKV(0, 0);
    loadBias(0, bbA);
    asm volatile("s_waitcnt vmcnt(4)" ::: "memory");
    __builtin_amdgcn_s_barrier();
    __builtin_amdgcn_sched_barrier(0);

    for (int tp = 0; tp < NT / 2; ++tp) {
        tile(tp * 2,     0, bbA, bbB);
        tile(tp * 2 + 1, 1, bbB, bbA);
    }

#pragma unroll
    for (int j = 0; j < 4; ++j) {
        int row = q0 + lg * 4 + j;
        if (row < N_) {
            float inv = 1.f / osum[j];
#pragma unroll
            for (int ft = 0; ft < 4; ++ft)
                stnt(&out[((size_t)(b * N_ + row)) * D_ + h * HD_ + ft * 16 + lr],
                     o[ft][j] * inv);
        }
    }
}

// ---------------------------------------------------------------- launch
extern "C" void kernel_launch(void* const* d_in, const int* in_sizes, int n_in,
                              void* d_out, int out_size, void* d_ws, size_t ws_size,
                              hipStream_t stream)
{
    const float* hs    = (const float*)d_in[0];
    const float* q_w   = (const float*)d_in[1];
    const float* q_b   = (const float*)d_in[2];
    const float* k_w   = (const float*)d_in[3];
    const float* v_w   = (const float*)d_in[4];
    const float* v_b   = (const float*)d_in[5];
    const float* table = (const float*)d_in[6];
    const int*   rpi   = (const int*)d_in[7];
    float* out = (float*)d_out;

    char* ws = (char*)d_ws;
    size_t off = 0;
    auto alloc = [&](size_t bytes) {
        char* p = ws + off;
        off = (off + bytes + 255) & ~(size_t)255;
        return p;
    };
    bf16_t* hb  = (bf16_t*)alloc((size_t)M_ * D_ * 2);
    bf16_t* Wc  = (bf16_t*)alloc((size_t)NW_ * D_ * 2);
    bf16_t* Qb  = (bf16_t*)alloc((size_t)B_ * H_ * N_ * HD_ * 2);
    bf16_t* Kb  = (bf16_t*)alloc((size_t)B_ * H_ * N_ * HD_ * 2 + 16384); // +pad rows
    bf16_t* VTb = (bf16_t*)alloc((size_t)B_ * H_ * HD_ * VN_ * 2);
    float*  bia = (float*)alloc((size_t)H_ * BPAD_ * BPAD_ * 4);

    int n4h = M_ * D_ / 4;
    cvt_f32_bf16<<<(n4h + 255) / 256, 256, 0, stream>>>(hs, hb, n4h);
    int n4w = D_ * D_ / 4;
    cvt3_f32_bf16<<<dim3((n4w + 255) / 256, 3), 256, 0, stream>>>(
        q_w, k_w, v_w, Wc, n4w);
    build_bias2<<<BPAD_, 256, 0, stream>>>(table, rpi, bia);

    qkv_gemm<<<2610, 256, 0, stream>>>(hb, Wc, q_b, v_b, Qb, Kb, VTb);

    attn<<<3840, 256, 0, stream>>>(Qb, Kb, VTb, bia, out);
}

// Round 17
// 215.279 us; speedup vs baseline: 1.0331x; 1.0331x over previous
//
#include <hip/hip_runtime.h>
#include <hip/hip_bf16.h>

#define B_  32
#define N_  577
#define D_  768
#define H_  12
#define HD_ 64
#define M_  (B_ * N_)        // 18464 rows
#define NW_ (3 * D_)         // 2304 fused output cols (q|k|v)
#define VN_ 640              // padded V row stride
#define BPAD_ 640            // bias: padded q-rows AND key-cols
#define SCALE_ 0.18033688f   // 0.125 * log2(e)  (pre-applied to Q)

typedef __bf16 bf16_t;
typedef __bf16 bf16x8 __attribute__((ext_vector_type(8)));
typedef __bf16 bf16x4 __attribute__((ext_vector_type(4)));
typedef float  f32x4  __attribute__((ext_vector_type(4)));

static __device__ __forceinline__ bf16x8 ldg8(const bf16_t* p) {
    return *reinterpret_cast<const bf16x8*>(p);
}

// within-64 key permutation: LDS K-slot s holds global key g(s) so that the
// swapped-QK output registers are directly the PV A-fragment (natural V order)
#define GPERM(r) (((r) & 32) | (((r) & 8) << 1) | (((r) & 4) << 1) | \
                  (((r) & 16) >> 2) | ((r) & 3))

#define GLOAD_LDS16(g, l)                                                     \
    __builtin_amdgcn_global_load_lds(                                         \
        (const __attribute__((address_space(1))) void*)(g),                   \
        (__attribute__((address_space(3))) void*)(l), 16, 0, 0)

// ---------------------------------------------------------------- fp32->bf16
__global__ void cvt_f32_bf16(const float* __restrict__ src,
                             bf16_t* __restrict__ dst, int n4) {
    int i = blockIdx.x * blockDim.x + threadIdx.x;
    if (i < n4) {
        float4 f = reinterpret_cast<const float4*>(src)[i];
        bf16x4 o;
        o.x = (bf16_t)f.x; o.y = (bf16_t)f.y; o.z = (bf16_t)f.z; o.w = (bf16_t)f.w;
        *reinterpret_cast<bf16x4*>(dst + (size_t)i * 4) = o;
    }
}

__global__ void cvt3_f32_bf16(const float* __restrict__ s0,
                              const float* __restrict__ s1,
                              const float* __restrict__ s2,
                              bf16_t* __restrict__ dst, int n4) {
    int i = blockIdx.x * blockDim.x + threadIdx.x;
    if (i < n4) {
        const float* src = blockIdx.y == 0 ? s0 : (blockIdx.y == 1 ? s1 : s2);
        float4 f = reinterpret_cast<const float4*>(src)[i];
        bf16x4 o;
        o.x = (bf16_t)f.x; o.y = (bf16_t)f.y; o.z = (bf16_t)f.z; o.w = (bf16_t)f.w;
        *reinterpret_cast<bf16x4*>(dst + (size_t)blockIdx.y * n4 * 4 + (size_t)i * 4) = o;
    }
}

// ---------------------------------------------------------------- bias build
// bias2[h][q][kl]: kl is the PERMUTED key slot (gk = (kl&~63)|GPERM(kl&63));
// slots whose global key >= N_ get -1e30 (kills padded keys via MFMA C-init).
__global__ void build_bias2(const float* __restrict__ table,
                            const int* __restrict__ idx,
                            float* __restrict__ bias2) {
    int q = blockIdx.x;                    // 0..639
    int rr = q < N_ ? q : (N_ - 1);
    for (int kl = threadIdx.x; kl < BPAD_; kl += blockDim.x) {
        int s = kl & 63;
        int gk = (kl & ~63) | GPERM(s);
        if (gk < N_) {
            int id = idx[rr * N_ + gk];
            const float* trow = table + (size_t)id * H_;
#pragma unroll
            for (int h = 0; h < H_; ++h)
                bias2[((size_t)h * BPAD_ + q) * BPAD_ + kl] =
                    trow[h] * 1.44269504f;
        } else {
#pragma unroll
            for (int h = 0; h < H_; ++h)
                bias2[((size_t)h * BPAD_ + q) * BPAD_ + kl] = -1e30f;
        }
    }
}

// ---------------------------------------------------------------- QKV GEMM
// (round-13 version: 128x128 tile, BK=64, dbuf + counted vmcnt(8))
__global__ __launch_bounds__(256) void qkv_gemm(
    const bf16_t* __restrict__ hb, const bf16_t* __restrict__ W,
    const float* __restrict__ qb, const float* __restrict__ vb,
    bf16_t* __restrict__ Q, bf16_t* __restrict__ K, bf16_t* __restrict__ VT)
{
    __shared__ __align__(16) char lds[65536];  // A:[2][16K] @0, B:[2][16K] @32K

    int tid = threadIdx.x;
    int w  = tid >> 6, l = tid & 63;
    int lr = l & 15, lg = l >> 4;
    int wm = w & 1,  wn = w >> 1;

    int wg = blockIdx.x;
    int xcd = wg & 7, pos = wg >> 3;
    const int Q8 = 2610 / 8, R8 = 2610 % 8;   // 326, 2
    int base = xcd < R8 ? xcd * (Q8 + 1) : R8 * (Q8 + 1) + (xcd - R8) * Q8;
    int wgid = base + pos;
    int bx = wgid / 18, y = wgid - bx * 18;
    int brow = bx * 128;
    int mat = y / 6, ysub = y - mat * 6;
    int cbase = ysub * 128;

    int srow = tid >> 3;
    int sslot = (tid & 7) ^ (srow & 7);
    const bf16_t* pa[4];
    const bf16_t* pb[4];
#pragma unroll
    for (int r = 0; r < 4; ++r) {
        int ra = brow + r * 32 + srow; ra = ra < M_ ? ra : (M_ - 1);
        pa[r] = hb + (size_t)ra * D_ + sslot * 8;
        pb[r] = W + (size_t)(y * 128 + r * 32 + srow) * D_ + sslot * 8;
    }

    auto stage = [&](int buf, int k) {
#pragma unroll
        for (int r = 0; r < 4; ++r) {
            GLOAD_LDS16(pa[r] + k, lds + buf * 16384 + r * 4096 + tid * 16);
            GLOAD_LDS16(pb[r] + k, lds + 32768 + buf * 16384 + r * 4096 + tid * 16);
        }
    };

    f32x4 acc[4][4] = {};
    stage(0, 0);
    int cur = 0;
    for (int t = 0; t < 12; ++t) {
        if (t < 11) {
            stage(cur ^ 1, (t + 1) * 64);
            asm volatile("s_waitcnt vmcnt(8)" ::: "memory");
        } else {
            asm volatile("s_waitcnt vmcnt(0)" ::: "memory");
        }
        __builtin_amdgcn_s_barrier();
        __builtin_amdgcn_sched_barrier(0);

        const char* pA = lds + cur * 16384;
        const char* pB = lds + 32768 + cur * 16384;
#pragma unroll
        for (int kk = 0; kk < 2; ++kk) {
            bf16x8 af[4];
#pragma unroll
            for (int m = 0; m < 4; ++m) {
                int row = wm * 64 + m * 16 + lr;
                af[m] = *reinterpret_cast<const bf16x8*>(
                    pA + row * 128 + (((kk * 4 + lg) ^ (lr & 7)) << 4));
            }
#pragma unroll
            for (int n = 0; n < 4; ++n) {
                int row = wn * 64 + n * 16 + lr;
                bf16x8 bfr = *reinterpret_cast<const bf16x8*>(
                    pB + row * 128 + (((kk * 4 + lg) ^ (lr & 7)) << 4));
#pragma unroll
                for (int m = 0; m < 4; ++m)
                    acc[m][n] = __builtin_amdgcn_mfma_f32_16x16x32_bf16(
                        af[m], bfr, acc[m][n], 0, 0, 0);
            }
        }
        __builtin_amdgcn_sched_barrier(0);
        __builtin_amdgcn_s_barrier();
        cur ^= 1;
    }

    bf16_t* ep = (bf16_t*)lds;
    if (mat < 2) {
#pragma unroll
        for (int m = 0; m < 4; ++m)
#pragma unroll
            for (int n = 0; n < 4; ++n) {
                int col = wn * 64 + n * 16 + lr;
#pragma unroll
                for (int j = 0; j < 4; ++j) {
                    int row = wm * 64 + m * 16 + lg * 4 + j;
                    float v = acc[m][n][j];
                    v = (mat == 0) ? (v + qb[cbase + col]) * SCALE_ : v;
                    ep[row * 132 + col] = (bf16_t)v;
                }
            }
        __syncthreads();
        bf16_t* dst0 = (mat == 0) ? Q : K;
#pragma unroll
        for (int k = 0; k < 8; ++k) {
            int c = k * 256 + tid;
            int row = c >> 4, cc = c & 15;
            int grow = brow + row;
            if (grow < M_) {
                int bb = grow / N_, nn = grow - bb * N_;
                int col0 = cc * 8;
                int hh = ysub * 2 + (col0 >> 6);
                int hd0 = col0 & 63;
                bf16x8 vc = *reinterpret_cast<const bf16x8*>(ep + row * 132 + col0);
                *reinterpret_cast<bf16x8*>(
                    dst0 + ((size_t)(bb * H_ + hh) * N_ + nn) * HD_ + hd0) = vc;
            }
        }
    } else {
#pragma unroll
        for (int m = 0; m < 4; ++m)
#pragma unroll
            for (int n = 0; n < 4; ++n) {
                int col = wn * 64 + n * 16 + lr;
                float badd = vb[cbase + col];
#pragma unroll
                for (int j = 0; j < 4; ++j) {
                    int row = wm * 64 + m * 16 + lg * 4 + j;
                    ep[col * 132 + row] = (bf16_t)(acc[m][n][j] + badd);
                }
            }
        __syncthreads();
#pragma unroll
        for (int k = 0; k < 8; ++k) {
            int c = k * 256 + tid;
            int col = c >> 4, rc = c & 15;
            int grow0 = brow + rc * 8;
            int hh = ysub * 2 + (col >> 6), hd = col & 63;
            int bb = grow0 / N_, nn0 = grow0 - bb * N_;
            if (nn0 + 8 <= N_ && grow0 + 8 <= M_) {
                *reinterpret_cast<bf16x8*>(
                    VT + ((size_t)(bb * H_ + hh) * HD_ + hd) * VN_ + nn0) =
                    *reinterpret_cast<const bf16x8*>(ep + col * 132 + rc * 8);
            } else {
                for (int jj = 0; jj < 8; ++jj) {
                    int grow = grow0 + jj;
                    if (grow >= M_) break;
                    int b2 = grow / N_, n2 = grow - b2 * N_;
                    VT[((size_t)(b2 * H_ + hh) * HD_ + hd) * VN_ + n2] =
                        ep[col * 132 + rc * 8 + jj];
                }
            }
        }
    }
}

// ---------------------------------------------------------------- attention
// Swapped-QK^T with key-permuted K tile: S^T = mfma(K, Q, bias2) gives lane
// (q = lane&15) the P values whose post-exp2 registers ARE the PV A-fragment
// in natural V key order (GPERM aligns slots) -> P never touches LDS.
// One-barrier pipeline: K,V dbuf, bias reg-dbuf. LDS 32KB -> 5 blocks/CU.
__global__ __launch_bounds__(256) void attn(
    const bf16_t* __restrict__ Q, const bf16_t* __restrict__ K,
    const bf16_t* __restrict__ VT, const float* __restrict__ bias2,
    float* __restrict__ out)
{
    __shared__ __align__(16) char Kl[2][8192];   // [64 key-slot][64 hd] swz
    __shared__ __align__(16) char Vl[2][8192];   // [64 d][64 key] swz
    // 32768 B -> 5 blocks/CU

    int tid = threadIdx.x;
    int w = tid >> 6, l = tid & 63, lr = l & 15, lg = l >> 4;

    int wg = blockIdx.x;
    int wgid = (wg & 7) * 480 + (wg >> 3);
    int h = wgid / 320;
    int rem = wgid - h * 320;
    int b = rem / 10;
    int qt = rem - b * 10;

    const bf16_t* Qp = Q  + (size_t)(b * H_ + h) * N_ * HD_;
    const bf16_t* Kp = K  + (size_t)(b * H_ + h) * N_ * HD_;
    const bf16_t* Vp = VT + (size_t)(b * H_ + h) * HD_ * VN_;
    const float*  bp = bias2 + (size_t)h * BPAD_ * BPAD_;   // [q][kl]

    int q0 = qt * 64 + w * 16;
    int qrow = q0 + lr;
    int qrow_c = qrow < N_ ? qrow : (N_ - 1);
    bf16x8 aQ0 = ldg8(Qp + (size_t)qrow_c * HD_ + lg * 8);
    bf16x8 aQ1 = ldg8(Qp + (size_t)qrow_c * HD_ + 32 + lg * 8);

    bf16x8 vone;
#pragma unroll
    for (int i = 0; i < 8; ++i) vone[i] = (bf16_t)1.0f;

    int rloc = l >> 3;
    int cswz = (l & 7) ^ rloc;
    const bf16_t* Kst[2];
    const bf16_t* Vst[2];
#pragma unroll
    for (int rnd = 0; rnd < 2; ++rnd) {
        int r = rnd * 32 + w * 8 + rloc;         // LDS key-slot row
        int gk = GPERM(r);                        // global key for this slot
        Kst[rnd] = Kp + (size_t)gk * HD_ + cswz * 8;   // unclamped (padded buf)
        Vst[rnd] = Vp + (size_t)r * VN_ + cswz * 8;    // V natural (rows = d)
    }

    f32x4 o[4] = {};
    f32x4 osum = {};
    const int NT = 10;

    auto stageKV = [&](int buf, int k0) {
#pragma unroll
        for (int rnd = 0; rnd < 2; ++rnd)
            GLOAD_LDS16(Kst[rnd] + (size_t)k0 * HD_,
                        Kl[buf] + rnd * 4096 + w * 1024);
#pragma unroll
        for (int rnd = 0; rnd < 2; ++rnd)
            GLOAD_LDS16(Vst[rnd] + k0, Vl[buf] + rnd * 4096 + w * 1024);
    };
    auto loadBias = [&](int k0, f32x4* bbv) {
        const float* brow = bp + (size_t)(q0 + lr) * BPAD_ + k0;
#pragma unroll
        for (int kt = 0; kt < 4; ++kt)
            bbv[kt] = *reinterpret_cast<const f32x4*>(brow + kt * 16 + lg * 4);
    };

    auto tile = [&](int t, int rbuf, const f32x4* bbcur, f32x4* bbnxt) {
        int k0 = t * 64;
        if (t + 1 < NT) {
            stageKV(rbuf ^ 1, k0 + 64);
            loadBias(k0 + 64, bbnxt);
        }
        __builtin_amdgcn_sched_barrier(0);

        // S^T = K Q^T + bias2 (swapped operands: D col = q, row = key-slot)
        f32x4 s[4];
        __builtin_amdgcn_s_setprio(1);
#pragma unroll
        for (int kt = 0; kt < 4; ++kt) {
            int r = kt * 16 + lr;                // key-slot row in Kl
            bf16x8 kf0 = *reinterpret_cast<const bf16x8*>(
                Kl[rbuf] + r * 128 + ((lg ^ (r & 7)) << 4));
            bf16x8 kf1 = *reinterpret_cast<const bf16x8*>(
                Kl[rbuf] + r * 128 + (((4 + lg) ^ (r & 7)) << 4));
            f32x4 a = __builtin_amdgcn_mfma_f32_16x16x32_bf16(
                kf0, aQ0, bbcur[kt], 0, 0, 0);
            s[kt] = __builtin_amdgcn_mfma_f32_16x16x32_bf16(kf1, aQ1, a, 0, 0, 0);
        }
        __builtin_amdgcn_s_setprio(0);

        // P = exp2(s) stays in registers; lane's s[2kc],[2kc+1] are the PV
        // A-fragment for keys kc*32 + lg*8 + (0..7) in natural V order.
        float p[4][4];
#pragma unroll
        for (int kt = 0; kt < 4; ++kt)
#pragma unroll
            for (int j = 0; j < 4; ++j)
                p[kt][j] = __builtin_amdgcn_exp2f(s[kt][j]);

        // O += P V ; row-sum += P * ones
        __builtin_amdgcn_s_setprio(1);
#pragma unroll
        for (int kc = 0; kc < 2; ++kc) {
            bf16x8 aP;
            aP[0] = (bf16_t)p[2 * kc][0];
            aP[1] = (bf16_t)p[2 * kc][1];
            aP[2] = (bf16_t)p[2 * kc][2];
            aP[3] = (bf16_t)p[2 * kc][3];
            aP[4] = (bf16_t)p[2 * kc + 1][0];
            aP[5] = (bf16_t)p[2 * kc + 1][1];
            aP[6] = (bf16_t)p[2 * kc + 1][2];
            aP[7] = (bf16_t)p[2 * kc + 1][3];
            osum = __builtin_amdgcn_mfma_f32_16x16x32_bf16(aP, vone, osum, 0, 0, 0);
#pragma unroll
            for (int ft = 0; ft < 4; ++ft) {
                int d = ft * 16 + lr;
                bf16x8 bV = *reinterpret_cast<const bf16x8*>(
                    Vl[rbuf] + d * 128 + (((kc * 4 + lg) ^ (d & 7)) << 4));
                o[ft] = __builtin_amdgcn_mfma_f32_16x16x32_bf16(aP, bV, o[ft], 0, 0, 0);
            }
        }
        __builtin_amdgcn_s_setprio(0);
        __builtin_amdgcn_sched_barrier(0);

        if (t + 1 < NT) asm volatile("s_waitcnt vmcnt(4)" ::: "memory");
        else            asm volatile("s_waitcnt vmcnt(0)" ::: "memory");
        __builtin_amdgcn_s_barrier();
        __builtin_amdgcn_sched_barrier(0);
    };

    f32x4 bbA[4], bbB[4];
    stageKV(0, 0);
    loadBias(0, bbA);
    asm volatile("s_waitcnt vmcnt(4)" ::: "memory");
    __builtin_amdgcn_s_barrier();
    __builtin_amdgcn_sched_barrier(0);

    for (int tp = 0; tp < NT / 2; ++tp) {
        tile(tp * 2,     0, bbA, bbB);
        tile(tp * 2 + 1, 1, bbB, bbA);
    }

    // D layout (col = d = lane&15 via B, row = q = lg*4+j): same store as
    // the unswapped version.
#pragma unroll
    for (int j = 0; j < 4; ++j) {
        int row = q0 + lg * 4 + j;
        if (row < N_) {
            float inv = 1.f / osum[j];
#pragma unroll
            for (int ft = 0; ft < 4; ++ft)
                out[((size_t)(b * N_ + row)) * D_ + h * HD_ + ft * 16 + lr] =
                    o[ft][j] * inv;
        }
    }
}

// ---------------------------------------------------------------- launch
extern "C" void kernel_launch(void* const* d_in, const int* in_sizes, int n_in,
                              void* d_out, int out_size, void* d_ws, size_t ws_size,
                              hipStream_t stream)
{
    const float* hs    = (const float*)d_in[0];
    const float* q_w   = (const float*)d_in[1];
    const float* q_b   = (const float*)d_in[2];
    const float* k_w   = (const float*)d_in[3];
    const float* v_w   = (const float*)d_in[4];
    const float* v_b   = (const float*)d_in[5];
    const float* table = (const float*)d_in[6];
    const int*   rpi   = (const int*)d_in[7];
    float* out = (float*)d_out;

    char* ws = (char*)d_ws;
    size_t off = 0;
    auto alloc = [&](size_t bytes) {
        char* p = ws + off;
        off = (off + bytes + 255) & ~(size_t)255;
        return p;
    };
    bf16_t* hb  = (bf16_t*)alloc((size_t)M_ * D_ * 2);
    bf16_t* Wc  = (bf16_t*)alloc((size_t)NW_ * D_ * 2);
    bf16_t* Qb  = (bf16_t*)alloc((size_t)B_ * H_ * N_ * HD_ * 2);
    bf16_t* Kb  = (bf16_t*)alloc((size_t)B_ * H_ * N_ * HD_ * 2 + 16384); // +pad rows
    bf16_t* VTb = (bf16_t*)alloc((size_t)B_ * H_ * HD_ * VN_ * 2);
    float*  bia = (float*)alloc((size_t)H_ * BPAD_ * BPAD_ * 4);

    int n4h = M_ * D_ / 4;
    cvt_f32_bf16<<<(n4h + 255) / 256, 256, 0, stream>>>(hs, hb, n4h);
    int n4w = D_ * D_ / 4;
    cvt3_f32_bf16<<<dim3((n4w + 255) / 256, 3), 256, 0, stream>>>(
        q_w, k_w, v_w, Wc, n4w);
    build_bias2<<<BPAD_, 256, 0, stream>>>(table, rpi, bia);

    qkv_gemm<<<2610, 256, 0, stream>>>(hb, Wc, q_b, v_b, Qb, Kb, VTb);

    attn<<<3840, 256, 0, stream>>>(Qb, Kb, VTb, bia, out);
}

// Round 18
// 210.459 us; speedup vs baseline: 1.0567x; 1.0229x over previous
//
#include <hip/hip_runtime.h>
#include <hip/hip_bf16.h>

#define B_  32
#define N_  577
#define D_  768
#define H_  12
#define HD_ 64
#define M_  (B_ * N_)        // 18464 rows
#define NW_ (3 * D_)         // 2304 fused output cols (q|k|v)
#define VN_ 640              // padded V row stride
#define BPAD_ 640            // bias: padded q-rows AND key-cols
#define SCALE_ 0.18033688f   // 0.125 * log2(e)  (pre-applied to Q)

typedef __bf16 bf16_t;
typedef __bf16 bf16x8 __attribute__((ext_vector_type(8)));
typedef __bf16 bf16x4 __attribute__((ext_vector_type(4)));
typedef float  f32x4  __attribute__((ext_vector_type(4)));

static __device__ __forceinline__ bf16x8 ldg8(const bf16_t* p) {
    return *reinterpret_cast<const bf16x8*>(p);
}

// within-64 key permutation: LDS K-slot s holds global key g(s) so that the
// swapped-QK output registers are directly the PV A-fragment (natural V order)
#define GPERM(r) (((r) & 32) | (((r) & 8) << 1) | (((r) & 4) << 1) | \
                  (((r) & 16) >> 2) | ((r) & 3))

#define GLOAD_LDS16(g, l)                                                     \
    __builtin_amdgcn_global_load_lds(                                         \
        (const __attribute__((address_space(1))) void*)(g),                   \
        (__attribute__((address_space(3))) void*)(l), 16, 0, 0)

// ---------------------------------------------------------------- fp32->bf16
__global__ void cvt_f32_bf16(const float* __restrict__ src,
                             bf16_t* __restrict__ dst, int n4) {
    int i = blockIdx.x * blockDim.x + threadIdx.x;
    if (i < n4) {
        float4 f = reinterpret_cast<const float4*>(src)[i];
        bf16x4 o;
        o.x = (bf16_t)f.x; o.y = (bf16_t)f.y; o.z = (bf16_t)f.z; o.w = (bf16_t)f.w;
        *reinterpret_cast<bf16x4*>(dst + (size_t)i * 4) = o;
    }
}

__global__ void cvt3_f32_bf16(const float* __restrict__ s0,
                              const float* __restrict__ s1,
                              const float* __restrict__ s2,
                              bf16_t* __restrict__ dst, int n4) {
    int i = blockIdx.x * blockDim.x + threadIdx.x;
    if (i < n4) {
        const float* src = blockIdx.y == 0 ? s0 : (blockIdx.y == 1 ? s1 : s2);
        float4 f = reinterpret_cast<const float4*>(src)[i];
        bf16x4 o;
        o.x = (bf16_t)f.x; o.y = (bf16_t)f.y; o.z = (bf16_t)f.z; o.w = (bf16_t)f.w;
        *reinterpret_cast<bf16x4*>(dst + (size_t)blockIdx.y * n4 * 4 + (size_t)i * 4) = o;
    }
}

// ---------------------------------------------------------------- bias build
__global__ void build_bias2(const float* __restrict__ table,
                            const int* __restrict__ idx,
                            float* __restrict__ bias2) {
    int q = blockIdx.x;                    // 0..639
    int rr = q < N_ ? q : (N_ - 1);
    for (int kl = threadIdx.x; kl < BPAD_; kl += blockDim.x) {
        int s = kl & 63;
        int gk = (kl & ~63) | GPERM(s);
        if (gk < N_) {
            int id = idx[rr * N_ + gk];
            const float* trow = table + (size_t)id * H_;
#pragma unroll
            for (int h = 0; h < H_; ++h)
                bias2[((size_t)h * BPAD_ + q) * BPAD_ + kl] =
                    trow[h] * 1.44269504f;
        } else {
#pragma unroll
            for (int h = 0; h < H_; ++h)
                bias2[((size_t)h * BPAD_ + q) * BPAD_ + kl] = -1e30f;
        }
    }
}

// ---------------------------------------------------------------- QKV GEMM
// 256x256 tile, 512 threads (8 waves, 2Mx4N), BK=32, RING of 4 LDS buffers
// with 3-deep counted-vmcnt prefetch (T3+T4): per K-step exactly one
// vmcnt(8) + one s_barrier; stages t+1,t+2 stay in flight across barriers.
// WAR-safe: stage(t+3) (issued after barrier t) overwrites buf((t-1)&3),
// whose last readers all passed that barrier. Swizzle pair = round-10's
// verified BK=32 geometry.
__global__ __launch_bounds__(512, 2) void qkv_gemm(
    const bf16_t* __restrict__ hb, const bf16_t* __restrict__ W,
    const float* __restrict__ qb, const float* __restrict__ vb,
    bf16_t* __restrict__ Q, bf16_t* __restrict__ K, bf16_t* __restrict__ VT)
{
    // A: bufs 0-3 @ [0, 65536); B: bufs 0-3 @ [65536, 131072); 16KB each.
    // Epilogue reuses the first ~68KB.
    __shared__ __align__(16) char lds[131072];

    int tid = threadIdx.x;
    int w  = tid >> 6, l = tid & 63;
    int lr = l & 15, lg = l >> 4;
    int wm = w >> 2, wn = w & 3;          // 2M x 4N wave grid

    // grid decode: 657 blocks, bijective XCD chunk (q=82, r=1), ct-fast
    int wg = blockIdx.x;
    int xcd = wg & 7, pos = wg >> 3;
    int base = (xcd == 0) ? 0 : 83 + (xcd - 1) * 82;
    int wgid = base + pos;
    int bx = wgid / 9, ct = wgid - bx * 9;
    int brow = bx * 256;
    int mat = ct / 3, csub = ct - mat * 3;
    int cbase = csub * 256;               // col offset within matrix

    // staging: pass r covers rows r*128 + (tid>>2); slot = tid&3 (16B units)
    // LDS[row][s] = G[row][s ^ ((row>>1)&3)]
    int srow = tid >> 2;                        // 0..127
    int sslot = (tid & 3) ^ ((srow >> 1) & 3);  // pre-swizzled source slot
    const bf16_t* pa[2];
    const bf16_t* pb[2];
#pragma unroll
    for (int r = 0; r < 2; ++r) {
        int ra = brow + r * 128 + srow; ra = ra < M_ ? ra : (M_ - 1);
        pa[r] = hb + (size_t)ra * D_ + sslot * 8;
        pb[r] = W + (size_t)(ct * 256 + r * 128 + srow) * D_ + sslot * 8;
    }

    auto stage = [&](int buf, int k) {   // 4 loads/thread (2 A + 2 B)
#pragma unroll
        for (int r = 0; r < 2; ++r) {
            GLOAD_LDS16(pa[r] + k, lds + buf * 16384 + r * 8192 + tid * 16);
            GLOAD_LDS16(pb[r] + k, lds + 65536 + buf * 16384 + r * 8192 + tid * 16);
        }
    };

    f32x4 acc[8][4] = {};
    stage(0, 0);
    stage(1, 32);
    stage(2, 64);
    int xsw = (lr >> 1) & 3;   // read-side swizzle

#pragma unroll 4
    for (int t = 0; t < 24; ++t) {
        if (t < 22)       asm volatile("s_waitcnt vmcnt(8)" ::: "memory");
        else if (t == 22) asm volatile("s_waitcnt vmcnt(4)" ::: "memory");
        else              asm volatile("s_waitcnt vmcnt(0)" ::: "memory");
        __builtin_amdgcn_s_barrier();
        __builtin_amdgcn_sched_barrier(0);
        if (t + 3 < 24) stage((t + 3) & 3, (t + 3) * 32);
        __builtin_amdgcn_sched_barrier(0);

        const char* pA = lds + (t & 3) * 16384;
        const char* pB = lds + 65536 + (t & 3) * 16384;
        bf16x8 bf[4];
#pragma unroll
        for (int n = 0; n < 4; ++n) {
            int row = wn * 64 + n * 16 + lr;
            bf[n] = *reinterpret_cast<const bf16x8*>(
                pB + row * 64 + ((lg ^ xsw) << 4));
        }
        __builtin_amdgcn_s_setprio(1);
#pragma unroll
        for (int m = 0; m < 8; ++m) {
            int row = wm * 128 + m * 16 + lr;
            bf16x8 af = *reinterpret_cast<const bf16x8*>(
                pA + row * 64 + ((lg ^ xsw) << 4));
#pragma unroll
            for (int n = 0; n < 4; ++n)
                acc[m][n] = __builtin_amdgcn_mfma_f32_16x16x32_bf16(
                    af, bf[n], acc[m][n], 0, 0, 0);
        }
        __builtin_amdgcn_s_setprio(0);
        __builtin_amdgcn_sched_barrier(0);
        // no trailing barrier: next step's top barrier provides WAR safety
    }
    __syncthreads();   // K-loop LDS fully consumed before epilogue reuse

    // ---- epilogue: per 128-row half: acc -> LDS repack -> coalesced stores
    bf16_t* ep = (bf16_t*)lds;
    if (mat < 2) {
        bf16_t* dst0 = (mat == 0) ? Q : K;
#pragma unroll
        for (int hp = 0; hp < 2; ++hp) {
            if (wm == hp) {
#pragma unroll
                for (int m = 0; m < 8; ++m)
#pragma unroll
                    for (int n = 0; n < 4; ++n) {
                        int col = wn * 64 + n * 16 + lr;
                        float badd = (mat == 0) ? qb[cbase + col] : 0.f;
#pragma unroll
                        for (int j = 0; j < 4; ++j) {
                            int rl = m * 16 + lg * 4 + j;   // 0..127
                            float v = acc[m][n][j];
                            v = (mat == 0) ? (v + badd) * SCALE_ : v;
                            ep[rl * 260 + col] = (bf16_t)v;
                        }
                    }
            }
            __syncthreads();
#pragma unroll
            for (int k = 0; k < 8; ++k) {
                int c = k * 512 + tid;          // 0..4095
                int row = c >> 5, chunk = c & 31;
                int col0 = chunk * 8;
                int grow = brow + hp * 128 + row;
                if (grow < M_) {
                    int bb = grow / N_, nn = grow - bb * N_;
                    int hh = csub * 4 + (col0 >> 6);
                    int hd0 = col0 & 63;
                    *reinterpret_cast<bf16x8*>(
                        dst0 + ((size_t)(bb * H_ + hh) * N_ + nn) * HD_ + hd0) =
                        *reinterpret_cast<const bf16x8*>(ep + row * 260 + col0);
                }
            }
            __syncthreads();
        }
    } else {
        // VT: transpose repack ep[col*132 + row], per 128-row half
#pragma unroll
        for (int hp = 0; hp < 2; ++hp) {
            if (wm == hp) {
#pragma unroll
                for (int m = 0; m < 8; ++m)
#pragma unroll
                    for (int n = 0; n < 4; ++n) {
                        int col = wn * 64 + n * 16 + lr;
                        float badd = vb[cbase + col];
#pragma unroll
                        for (int j = 0; j < 4; ++j) {
                            int rl = m * 16 + lg * 4 + j;
                            ep[col * 132 + rl] = (bf16_t)(acc[m][n][j] + badd);
                        }
                    }
            }
            __syncthreads();
#pragma unroll
            for (int k = 0; k < 8; ++k) {
                int c = k * 512 + tid;          // 0..4095: col(256) x rc(16)
                int col = c >> 4, rc = c & 15;
                int grow0 = brow + hp * 128 + rc * 8;
                int hh = csub * 4 + (col >> 6), hd = col & 63;
                int bb = grow0 / N_, nn0 = grow0 - bb * N_;
                if (nn0 + 8 <= N_ && grow0 + 8 <= M_) {
                    *reinterpret_cast<bf16x8*>(
                        VT + ((size_t)(bb * H_ + hh) * HD_ + hd) * VN_ + nn0) =
                        *reinterpret_cast<const bf16x8*>(ep + col * 132 + rc * 8);
                } else {
                    for (int jj = 0; jj < 8; ++jj) {
                        int grow = grow0 + jj;
                        if (grow >= M_) break;
                        int b2 = grow / N_, n2 = grow - b2 * N_;
                        VT[((size_t)(b2 * H_ + hh) * HD_ + hd) * VN_ + n2] =
                            ep[col * 132 + rc * 8 + jj];
                    }
                }
            }
            __syncthreads();
        }
    }
}

// ---------------------------------------------------------------- attention
// (round-15/17 version — best measured. Swapped-QK^T, key-permuted K tile,
// P in registers; one-barrier pipeline; K,V dbuf; bias reg-dbuf.)
__global__ __launch_bounds__(256) void attn(
    const bf16_t* __restrict__ Q, const bf16_t* __restrict__ K,
    const bf16_t* __restrict__ VT, const float* __restrict__ bias2,
    float* __restrict__ out)
{
    __shared__ __align__(16) char Kl[2][8192];   // [64 key-slot][64 hd] swz
    __shared__ __align__(16) char Vl[2][8192];   // [64 d][64 key] swz
    // 32768 B -> 5 blocks/CU

    int tid = threadIdx.x;
    int w = tid >> 6, l = tid & 63, lr = l & 15, lg = l >> 4;

    int wg = blockIdx.x;
    int wgid = (wg & 7) * 480 + (wg >> 3);
    int h = wgid / 320;
    int rem = wgid - h * 320;
    int b = rem / 10;
    int qt = rem - b * 10;

    const bf16_t* Qp = Q  + (size_t)(b * H_ + h) * N_ * HD_;
    const bf16_t* Kp = K  + (size_t)(b * H_ + h) * N_ * HD_;
    const bf16_t* Vp = VT + (size_t)(b * H_ + h) * HD_ * VN_;
    const float*  bp = bias2 + (size_t)h * BPAD_ * BPAD_;   // [q][kl]

    int q0 = qt * 64 + w * 16;
    int qrow = q0 + lr;
    int qrow_c = qrow < N_ ? qrow : (N_ - 1);
    bf16x8 aQ0 = ldg8(Qp + (size_t)qrow_c * HD_ + lg * 8);
    bf16x8 aQ1 = ldg8(Qp + (size_t)qrow_c * HD_ + 32 + lg * 8);

    bf16x8 vone;
#pragma unroll
    for (int i = 0; i < 8; ++i) vone[i] = (bf16_t)1.0f;

    int rloc = l >> 3;
    int cswz = (l & 7) ^ rloc;
    const bf16_t* Kst[2];
    const bf16_t* Vst[2];
#pragma unroll
    for (int rnd = 0; rnd < 2; ++rnd) {
        int r = rnd * 32 + w * 8 + rloc;         // LDS key-slot row
        int gk = GPERM(r);                        // global key for this slot
        Kst[rnd] = Kp + (size_t)gk * HD_ + cswz * 8;   // unclamped (padded buf)
        Vst[rnd] = Vp + (size_t)r * VN_ + cswz * 8;    // V natural (rows = d)
    }

    f32x4 o[4] = {};
    f32x4 osum = {};
    const int NT = 10;

    auto stageKV = [&](int buf, int k0) {
#pragma unroll
        for (int rnd = 0; rnd < 2; ++rnd)
            GLOAD_LDS16(Kst[rnd] + (size_t)k0 * HD_,
                        Kl[buf] + rnd * 4096 + w * 1024);
#pragma unroll
        for (int rnd = 0; rnd < 2; ++rnd)
            GLOAD_LDS16(Vst[rnd] + k0, Vl[buf] + rnd * 4096 + w * 1024);
    };
    auto loadBias = [&](int k0, f32x4* bbv) {
        const float* brow = bp + (size_t)(q0 + lr) * BPAD_ + k0;
#pragma unroll
        for (int kt = 0; kt < 4; ++kt)
            bbv[kt] = *reinterpret_cast<const f32x4*>(brow + kt * 16 + lg * 4);
    };

    auto tile = [&](int t, int rbuf, const f32x4* bbcur, f32x4* bbnxt) {
        int k0 = t * 64;
        if (t + 1 < NT) {
            stageKV(rbuf ^ 1, k0 + 64);
            loadBias(k0 + 64, bbnxt);
        }
        __builtin_amdgcn_sched_barrier(0);

        // S^T = K Q^T + bias2 (swapped operands: D col = q, row = key-slot)
        f32x4 s[4];
        __builtin_amdgcn_s_setprio(1);
#pragma unroll
        for (int kt = 0; kt < 4; ++kt) {
            int r = kt * 16 + lr;                // key-slot row in Kl
            bf16x8 kf0 = *reinterpret_cast<const bf16x8*>(
                Kl[rbuf] + r * 128 + ((lg ^ (r & 7)) << 4));
            bf16x8 kf1 = *reinterpret_cast<const bf16x8*>(
                Kl[rbuf] + r * 128 + (((4 + lg) ^ (r & 7)) << 4));
            f32x4 a = __builtin_amdgcn_mfma_f32_16x16x32_bf16(
                kf0, aQ0, bbcur[kt], 0, 0, 0);
            s[kt] = __builtin_amdgcn_mfma_f32_16x16x32_bf16(kf1, aQ1, a, 0, 0, 0);
        }
        __builtin_amdgcn_s_setprio(0);

        // P = exp2(s) stays in registers; lane's s[2kc],[2kc+1] are the PV
        // A-fragment for keys kc*32 + lg*8 + (0..7) in natural V order.
        float p[4][4];
#pragma unroll
        for (int kt = 0; kt < 4; ++kt)
#pragma unroll
            for (int j = 0; j < 4; ++j)
                p[kt][j] = __builtin_amdgcn_exp2f(s[kt][j]);

        // O += P V ; row-sum += P * ones
        __builtin_amdgcn_s_setprio(1);
#pragma unroll
        for (int kc = 0; kc < 2; ++kc) {
            bf16x8 aP;
            aP[0] = (bf16_t)p[2 * kc][0];
            aP[1] = (bf16_t)p[2 * kc][1];
            aP[2] = (bf16_t)p[2 * kc][2];
            aP[3] = (bf16_t)p[2 * kc][3];
            aP[4] = (bf16_t)p[2 * kc + 1][0];
            aP[5] = (bf16_t)p[2 * kc + 1][1];
            aP[6] = (bf16_t)p[2 * kc + 1][2];
            aP[7] = (bf16_t)p[2 * kc + 1][3];
            osum = __builtin_amdgcn_mfma_f32_16x16x32_bf16(aP, vone, osum, 0, 0, 0);
#pragma unroll
            for (int ft = 0; ft < 4; ++ft) {
                int d = ft * 16 + lr;
                bf16x8 bV = *reinterpret_cast<const bf16x8*>(
                    Vl[rbuf] + d * 128 + (((kc * 4 + lg) ^ (d & 7)) << 4));
                o[ft] = __builtin_amdgcn_mfma_f32_16x16x32_bf16(aP, bV, o[ft], 0, 0, 0);
            }
        }
        __builtin_amdgcn_s_setprio(0);
        __builtin_amdgcn_sched_barrier(0);

        if (t + 1 < NT) asm volatile("s_waitcnt vmcnt(4)" ::: "memory");
        else            asm volatile("s_waitcnt vmcnt(0)" ::: "memory");
        __builtin_amdgcn_s_barrier();
        __builtin_amdgcn_sched_barrier(0);
    };

    f32x4 bbA[4], bbB[4];
    stageKV(0, 0);
    loadBias(0, bbA);
    asm volatile("s_waitcnt vmcnt(4)" ::: "memory");
    __builtin_amdgcn_s_barrier();
    __builtin_amdgcn_sched_barrier(0);

    for (int tp = 0; tp < NT / 2; ++tp) {
        tile(tp * 2,     0, bbA, bbB);
        tile(tp * 2 + 1, 1, bbB, bbA);
    }

#pragma unroll
    for (int j = 0; j < 4; ++j) {
        int row = q0 + lg * 4 + j;
        if (row < N_) {
            float inv = 1.f / osum[j];
#pragma unroll
            for (int ft = 0; ft < 4; ++ft)
                out[((size_t)(b * N_ + row)) * D_ + h * HD_ + ft * 16 + lr] =
                    o[ft][j] * inv;
        }
    }
}

// ---------------------------------------------------------------- launch
extern "C" void kernel_launch(void* const* d_in, const int* in_sizes, int n_in,
                              void* d_out, int out_size, void* d_ws, size_t ws_size,
                              hipStream_t stream)
{
    const float* hs    = (const float*)d_in[0];
    const float* q_w   = (const float*)d_in[1];
    const float* q_b   = (const float*)d_in[2];
    const float* k_w   = (const float*)d_in[3];
    const float* v_w   = (const float*)d_in[4];
    const float* v_b   = (const float*)d_in[5];
    const float* table = (const float*)d_in[6];
    const int*   rpi   = (const int*)d_in[7];
    float* out = (float*)d_out;

    char* ws = (char*)d_ws;
    size_t off = 0;
    auto alloc = [&](size_t bytes) {
        char* p = ws + off;
        off = (off + bytes + 255) & ~(size_t)255;
        return p;
    };
    bf16_t* hb  = (bf16_t*)alloc((size_t)M_ * D_ * 2);
    bf16_t* Wc  = (bf16_t*)alloc((size_t)NW_ * D_ * 2);
    bf16_t* Qb  = (bf16_t*)alloc((size_t)B_ * H_ * N_ * HD_ * 2);
    bf16_t* Kb  = (bf16_t*)alloc((size_t)B_ * H_ * N_ * HD_ * 2 + 16384); // +pad rows
    bf16_t* VTb = (bf16_t*)alloc((size_t)B_ * H_ * HD_ * VN_ * 2);
    float*  bia = (float*)alloc((size_t)H_ * BPAD_ * BPAD_ * 4);

    int n4h = M_ * D_ / 4;
    cvt_f32_bf16<<<(n4h + 255) / 256, 256, 0, stream>>>(hs, hb, n4h);
    int n4w = D_ * D_ / 4;
    cvt3_f32_bf16<<<dim3((n4w + 255) / 256, 3), 256, 0, stream>>>(
        q_w, k_w, v_w, Wc, n4w);
    build_bias2<<<BPAD_, 256, 0, stream>>>(table, rpi, bia);

    qkv_gemm<<<657, 512, 0, stream>>>(hb, Wc, q_b, v_b, Qb, Kb, VTb);

    attn<<<3840, 256, 0, stream>>>(Qb, Kb, VTb, bia, out);
}